// Round 3
// baseline (562.628 us; speedup 1.0000x reference)
//
#include <hip/hip_runtime.h>

// ---------- bf16 helpers (bf16 arrays handled as ushort) ----------
__device__ __forceinline__ float bf2f(unsigned int u16) {
    return __uint_as_float(u16 << 16);
}
__device__ __forceinline__ unsigned short f2bf(float f) {
    unsigned int u = __float_as_uint(f);
    unsigned int lsb = (u >> 16) & 1u;
    u += 0x7fffu + lsb;
    return (unsigned short)(u >> 16);
}

// ---------------- kernel 0: runtime encoding detection ----------------
// flags[0] = 1 if float inputs are bf16-packed, 0 if fp32
// flags[1] = 1 if edge_index is int64 (little-endian), 0 if int32
__global__ __launch_bounds__(256) void k_detect(const unsigned int* __restrict__ xw,
                                                const unsigned int* __restrict__ eiw,
                                                int* __restrict__ flags) {
    __shared__ int votes[2];
    int tid = threadIdx.x;
    if (tid == 0) { votes[0] = 0; votes[1] = 0; }
    __syncthreads();
    unsigned int w = xw[tid];
    unsigned int lo = w & 0xffffu;
    unsigned int elo = (lo >> 7) & 0xffu;
    int bfvote = (lo == 0u || (elo >= 100u && elo <= 140u)) ? 1 : 0;
    int nzvote = (eiw[2 * tid + 1] != 0u) ? 1 : 0;
    atomicAdd(&votes[0], bfvote);
    atomicAdd(&votes[1], nzvote);
    __syncthreads();
    if (tid == 0) {
        flags[0] = (votes[0] >= 160) ? 1 : 0;
        flags[1] = (votes[1] == 0) ? 1 : 0;
    }
}

// ---------------- kernel 1: in-degree over dst ----------------
__global__ __launch_bounds__(256) void k_deg(const int* __restrict__ ei,
                                             const int* __restrict__ flags,
                                             int* __restrict__ deg, int E, int Nn) {
    int e = blockIdx.x * 256 + threadIdx.x;
    if (e >= E) return;
    int is64 = flags[1];
    int d = is64 ? ei[2 * (E + e)] : ei[E + e];
    if ((unsigned)d >= (unsigned)Nn) return;  // defensive
    atomicAdd(&deg[d], 1);
}

// ---------------- scan kernels: exclusive scan of deg -> row_start/cursor ----------------
__global__ __launch_bounds__(256) void k_scan1(const int* __restrict__ deg,
                                               int* __restrict__ row_tmp,
                                               int* __restrict__ bsum, int Nn) {
    __shared__ int sbuf[2][256];
    int tid = threadIdx.x;
    int i = blockIdx.x * 256 + tid;
    int v = (i < Nn) ? deg[i] : 0;
    sbuf[0][tid] = v;
    __syncthreads();
    int pi = 0;
    #pragma unroll
    for (int off = 1; off < 256; off <<= 1) {
        int nv = sbuf[pi][tid] + ((tid >= off) ? sbuf[pi][tid - off] : 0);
        __syncthreads();
        sbuf[pi ^ 1][tid] = nv;
        __syncthreads();
        pi ^= 1;
    }
    int incl = sbuf[pi][tid];
    if (i < Nn) row_tmp[i] = incl;
    if (tid == 255) bsum[blockIdx.x] = incl;
}

__global__ __launch_bounds__(512) void k_scan2(int* __restrict__ bsum, int G) {
    // single block; handles G up to 512*chunks via running offset
    __shared__ int sbuf[2][512];
    int tid = threadIdx.x;
    int run = 0;
    for (int base = 0; base < G; base += 512) {
        int idx = base + tid;
        int v = (idx < G) ? bsum[idx] : 0;
        sbuf[0][tid] = v;
        __syncthreads();
        int pi = 0;
        #pragma unroll
        for (int off = 1; off < 512; off <<= 1) {
            int nv = sbuf[pi][tid] + ((tid >= off) ? sbuf[pi][tid - off] : 0);
            __syncthreads();
            sbuf[pi ^ 1][tid] = nv;
            __syncthreads();
            pi ^= 1;
        }
        int incl = sbuf[pi][tid];
        if (idx < G) bsum[idx] = run + incl - v;  // exclusive
        int tot = sbuf[pi][511];
        __syncthreads();
        run += tot;
    }
}

__global__ __launch_bounds__(256) void k_scan3(const int* __restrict__ deg,
                                               const int* __restrict__ row_tmp,
                                               const int* __restrict__ bsum,
                                               int* __restrict__ row_start,
                                               int* __restrict__ cursor, int Nn) {
    int tid = threadIdx.x;
    int i = blockIdx.x * 256 + tid;
    if (i >= Nn) return;
    int ex = row_tmp[i] - deg[i] + bsum[blockIdx.x];
    row_start[i] = ex;
    cursor[i] = ex;
}

// ---------------- kernel: hs = (x @ W1) * dinv, also writes dinv ----------------
// block = 256 threads, 256 nodes/block; thread = (nodeq 0..63, hq 0..3)
__global__ __launch_bounds__(256) void k_gemm1(const void* __restrict__ xraw,
                                               const void* __restrict__ w1raw,
                                               const int* __restrict__ flags,
                                               const int* __restrict__ deg,
                                               float* __restrict__ hs,
                                               float* __restrict__ dinv, int Nn) {
    __shared__ float sWt[16 * 132];  // W1^T [hid][k], padded rows
    const int isbf = flags[0];
    const ushort* xb = (const ushort*)xraw;
    const float* xf = (const float*)xraw;
    int tid = threadIdx.x;
    if (isbf) {
        const ushort* w1 = (const ushort*)w1raw;
        for (int i = tid; i < 2048; i += 256) {
            int k = i >> 4, j = i & 15;
            sWt[j * 132 + k] = bf2f(w1[i]);
        }
    } else {
        const float* w1 = (const float*)w1raw;
        for (int i = tid; i < 2048; i += 256) {
            int k = i >> 4, j = i & 15;
            sWt[j * 132 + k] = w1[i];
        }
    }
    __syncthreads();
    int hq = tid & 3;
    int nodeq = tid >> 2;
    int n0 = blockIdx.x * 256 + nodeq * 4;
    float acc[4][4] = {};
    for (int ko = 0; ko < 16; ++ko) {
        float xv[4][8];
        #pragma unroll
        for (int r = 0; r < 4; ++r) {
            int n = n0 + r;
            if (n < Nn) {
                if (isbf) {
                    uint4 q = *reinterpret_cast<const uint4*>(xb + (size_t)n * 128 + ko * 8);
                    xv[r][0] = bf2f(q.x & 0xffffu); xv[r][1] = bf2f(q.x >> 16);
                    xv[r][2] = bf2f(q.y & 0xffffu); xv[r][3] = bf2f(q.y >> 16);
                    xv[r][4] = bf2f(q.z & 0xffffu); xv[r][5] = bf2f(q.z >> 16);
                    xv[r][6] = bf2f(q.w & 0xffffu); xv[r][7] = bf2f(q.w >> 16);
                } else {
                    const float4* p = reinterpret_cast<const float4*>(xf + (size_t)n * 128 + ko * 8);
                    float4 a = p[0], b = p[1];
                    xv[r][0] = a.x; xv[r][1] = a.y; xv[r][2] = a.z; xv[r][3] = a.w;
                    xv[r][4] = b.x; xv[r][5] = b.y; xv[r][6] = b.z; xv[r][7] = b.w;
                }
            } else {
                #pragma unroll
                for (int u = 0; u < 8; ++u) xv[r][u] = 0.f;
            }
        }
        #pragma unroll
        for (int c = 0; c < 4; ++c) {
            const float* wr = &sWt[(hq * 4 + c) * 132 + ko * 8];
            float4 w0 = *reinterpret_cast<const float4*>(wr);
            float4 w1v = *reinterpret_cast<const float4*>(wr + 4);
            #pragma unroll
            for (int r = 0; r < 4; ++r) {
                acc[r][c] += xv[r][0] * w0.x + xv[r][1] * w0.y + xv[r][2] * w0.z + xv[r][3] * w0.w
                           + xv[r][4] * w1v.x + xv[r][5] * w1v.y + xv[r][6] * w1v.z + xv[r][7] * w1v.w;
            }
        }
    }
    #pragma unroll
    for (int r = 0; r < 4; ++r) {
        int n = n0 + r;
        if (n < Nn) {
            float dv = rsqrtf((float)(deg[n] + 1));  // +1 self loop
            if (hq == 0) dinv[n] = dv;
            float4 o = make_float4(acc[r][0] * dv, acc[r][1] * dv, acc[r][2] * dv, acc[r][3] * dv);
            *reinterpret_cast<float4*>(hs + (size_t)n * 16 + hq * 4) = o;
        }
    }
}

// ---------------- kernel: CSR build (counting-sort scatter of src by dst) ----------------
__global__ __launch_bounds__(256) void k_csr(const int* __restrict__ ei,
                                             const int* __restrict__ flags,
                                             int* __restrict__ cursor,
                                             int* __restrict__ csr_src, int E, int Nn) {
    int e = blockIdx.x * 256 + threadIdx.x;
    if (e >= E) return;
    int is64 = flags[1];
    int s, d;
    if (is64) { s = ei[2 * e]; d = ei[2 * (E + e)]; }
    else      { s = ei[e];     d = ei[E + e]; }
    if ((unsigned)s >= (unsigned)Nn || (unsigned)d >= (unsigned)Nn) return;  // defensive
    int pos = atomicAdd(&cursor[d], 1);
    if ((unsigned)pos < (unsigned)E) csr_src[pos] = s;
}

// ---------------- kernel: gather-reduce + bias/relu + pool + softmax -> out ----------------
// 16 lanes per node, 16 nodes per block
__global__ __launch_bounds__(256) void k_gather(const int* __restrict__ row_start,
                                                const int* __restrict__ deg,
                                                const int* __restrict__ csr_src,
                                                const float* __restrict__ hs,
                                                const float* __restrict__ dinv,
                                                const void* __restrict__ b1raw,
                                                const void* __restrict__ wpraw,
                                                const void* __restrict__ bpraw,
                                                const int* __restrict__ flags,
                                                void* __restrict__ outraw, int Nn) {
    __shared__ float sWp[256];
    const int isbf = flags[0];
    int tid = threadIdx.x;
    sWp[tid] = isbf ? bf2f(((const ushort*)wpraw)[tid]) : ((const float*)wpraw)[tid];
    __syncthreads();
    int nl = tid >> 4, j = tid & 15;
    int n = blockIdx.x * 16 + nl;
    if (n >= Nn) return;
    float b1v = isbf ? bf2f(((const ushort*)b1raw)[j]) : ((const float*)b1raw)[j];
    float bpv = isbf ? bf2f(((const ushort*)bpraw)[j]) : ((const float*)bpraw)[j];
    int start = row_start[n];
    int cnt = deg[n];
    float acc0 = hs[(size_t)n * 16 + j];  // self-loop term (hs = h*dinv)
    float acc1 = 0.f;
    int k = 0;
    for (; k + 4 <= cnt; k += 4) {
        int s0 = csr_src[start + k];
        int s1 = csr_src[start + k + 1];
        int s2 = csr_src[start + k + 2];
        int s3 = csr_src[start + k + 3];
        float v0 = ((unsigned)s0 < (unsigned)Nn) ? hs[(size_t)s0 * 16 + j] : 0.f;
        float v1 = ((unsigned)s1 < (unsigned)Nn) ? hs[(size_t)s1 * 16 + j] : 0.f;
        float v2 = ((unsigned)s2 < (unsigned)Nn) ? hs[(size_t)s2 * 16 + j] : 0.f;
        float v3 = ((unsigned)s3 < (unsigned)Nn) ? hs[(size_t)s3 * 16 + j] : 0.f;
        acc0 += v0 + v2;
        acc1 += v1 + v3;
    }
    for (; k < cnt; ++k) {
        int s0 = csr_src[start + k];
        if ((unsigned)s0 < (unsigned)Nn) acc0 += hs[(size_t)s0 * 16 + j];
    }
    float r = fmaxf((acc0 + acc1) * dinv[n] + b1v, 0.f);
    // pooling: logit_j = bp_j + sum_k relu_k * Wp[k][j]
    float lg = bpv;
    #pragma unroll
    for (int kk = 0; kk < 16; ++kk) lg += __shfl(r, kk, 16) * sWp[kk * 16 + j];
    // softmax over the 16 lanes of this node
    float m = lg;
    #pragma unroll
    for (int off = 1; off < 16; off <<= 1) m = fmaxf(m, __shfl_xor(m, off, 16));
    float ev = __expf(lg - m);
    float ssum = ev;
    #pragma unroll
    for (int off = 1; off < 16; off <<= 1) ssum += __shfl_xor(ssum, off, 16);
    float v = ev / ssum;
    if (isbf) ((ushort*)outraw)[(size_t)n * 16 + j] = f2bf(v);
    else      ((float*)outraw)[(size_t)n * 16 + j] = v;
}

extern "C" void kernel_launch(void* const* d_in, const int* in_sizes, int n_in,
                              void* d_out, int out_size, void* d_ws, size_t ws_size,
                              hipStream_t stream) {
    const void* x  = d_in[0];             // [N,128]
    const void* W1 = d_in[1];             // [128,16]
    const void* b1 = d_in[2];             // [16]
    const void* Wp = d_in[3];             // [16,16]
    const void* bp = d_in[4];             // [16]
    const int*  ei = (const int*)d_in[5]; // [2,E] int32 or int64

    int Nn = in_sizes[0] / 128;
    int E  = in_sizes[5] / 2;

    size_t Ns = (size_t)Nn;
    char* ws = (char*)d_ws;
    size_t off = 0;
    auto alloc = [&](size_t bytes) { void* p = ws + off; off += (bytes + 63) & ~(size_t)63; return p; };
    int*   flags     = (int*)alloc(64);
    float* hs        = (float*)alloc(Ns * 16 * 4);
    float* dinv      = (float*)alloc(Ns * 4);
    int*   deg       = (int*)alloc(Ns * 4);
    int*   row_start = (int*)alloc(Ns * 4);
    int*   row_tmp   = (int*)alloc(Ns * 4);
    int*   cursor    = (int*)alloc(Ns * 4);
    int*   bsum      = (int*)alloc(4096);
    int*   csr_src   = (int*)alloc((size_t)E * 4);

    int G = (Nn + 255) / 256;        // scan grid
    int EB = (E + 255) / 256;        // edge grid

    hipMemsetAsync(deg, 0, Ns * 4, stream);
    k_detect<<<1, 256, 0, stream>>>((const unsigned int*)x, (const unsigned int*)ei, flags);
    k_deg<<<EB, 256, 0, stream>>>(ei, flags, deg, E, Nn);
    k_scan1<<<G, 256, 0, stream>>>(deg, row_tmp, bsum, Nn);
    k_scan2<<<1, 512, 0, stream>>>(bsum, G);
    k_scan3<<<G, 256, 0, stream>>>(deg, row_tmp, bsum, row_start, cursor, Nn);
    k_gemm1<<<G, 256, 0, stream>>>(x, W1, flags, deg, hs, dinv, Nn);
    k_csr<<<EB, 256, 0, stream>>>(ei, flags, cursor, csr_src, E, Nn);
    k_gather<<<(Nn + 15) / 16, 256, 0, stream>>>(row_start, deg, csr_src, hs, dinv,
                                                 b1, Wp, bp, flags, d_out, Nn);
}

// Round 4
// 434.450 us; speedup vs baseline: 1.2950x; 1.2950x over previous
//
#include <hip/hip_runtime.h>

// ---------- bf16 helpers (bf16 arrays handled as ushort) ----------
__device__ __forceinline__ float bf2f(unsigned int u16) {
    return __uint_as_float(u16 << 16);
}
__device__ __forceinline__ unsigned short f2bf(float f) {
    unsigned int u = __float_as_uint(f);
    unsigned int lsb = (u >> 16) & 1u;
    u += 0x7fffu + lsb;
    return (unsigned short)(u >> 16);
}

// HW fp32 global atomic add (global_atomic_add_f32), no CAS loop, no return wait
__device__ __forceinline__ void atomAddF(float* p, float v) {
#if defined(__has_builtin) && __has_builtin(__builtin_amdgcn_global_atomic_fadd_f32)
    unsafeAtomicAdd(p, v);
#else
    atomicAdd(p, v);
#endif
}

// ---------------- kernel 0: runtime encoding detection ----------------
// flags[0] = 1 if float inputs are bf16-packed, 0 if fp32
// flags[1] = 1 if edge_index is int64 (little-endian), 0 if int32
__global__ __launch_bounds__(256) void k_detect(const unsigned int* __restrict__ xw,
                                                const unsigned int* __restrict__ eiw,
                                                int* __restrict__ flags) {
    __shared__ int votes[2];
    int tid = threadIdx.x;
    if (tid == 0) { votes[0] = 0; votes[1] = 0; }
    __syncthreads();
    unsigned int w = xw[tid];
    unsigned int lo = w & 0xffffu;
    unsigned int elo = (lo >> 7) & 0xffu;
    int bfvote = (lo == 0u || (elo >= 100u && elo <= 140u)) ? 1 : 0;
    int nzvote = (eiw[2 * tid + 1] != 0u) ? 1 : 0;
    atomicAdd(&votes[0], bfvote);
    atomicAdd(&votes[1], nzvote);
    __syncthreads();
    if (tid == 0) {
        flags[0] = (votes[0] >= 160) ? 1 : 0;
        flags[1] = (votes[1] == 0) ? 1 : 0;
    }
}

// ---------------- kernel 1: in-degree over dst ----------------
__global__ __launch_bounds__(256) void k_deg(const int* __restrict__ ei,
                                             const int* __restrict__ flags,
                                             int* __restrict__ deg, int E, int Nn) {
    int e = blockIdx.x * 256 + threadIdx.x;
    if (e >= E) return;
    int is64 = flags[1];
    int d = is64 ? ei[2 * (E + e)] : ei[E + e];
    if ((unsigned)d >= (unsigned)Nn) return;  // defensive
    atomicAdd(&deg[d], 1);
}

// ---------------- kernel 2: hs = (x@W1)*dinv, agg0 = hs*dinv; writes dinv ----------------
// block = 256 threads, 256 nodes/block; thread = (nodeq 0..63, hq 0..3)
__global__ __launch_bounds__(256) void k_gemm1(const void* __restrict__ xraw,
                                               const void* __restrict__ w1raw,
                                               const int* __restrict__ flags,
                                               const int* __restrict__ deg,
                                               float* __restrict__ hs,
                                               float* __restrict__ agg,
                                               float* __restrict__ dinv, int Nn) {
    __shared__ float sWt[16 * 132];  // W1^T [hid][k], padded rows
    const int isbf = flags[0];
    const ushort* xb = (const ushort*)xraw;
    const float* xf = (const float*)xraw;
    int tid = threadIdx.x;
    if (isbf) {
        const ushort* w1 = (const ushort*)w1raw;
        for (int i = tid; i < 2048; i += 256) {
            int k = i >> 4, j = i & 15;
            sWt[j * 132 + k] = bf2f(w1[i]);
        }
    } else {
        const float* w1 = (const float*)w1raw;
        for (int i = tid; i < 2048; i += 256) {
            int k = i >> 4, j = i & 15;
            sWt[j * 132 + k] = w1[i];
        }
    }
    __syncthreads();
    int hq = tid & 3;
    int nodeq = tid >> 2;
    int n0 = blockIdx.x * 256 + nodeq * 4;
    float acc[4][4] = {};
    for (int ko = 0; ko < 16; ++ko) {
        float xv[4][8];
        #pragma unroll
        for (int r = 0; r < 4; ++r) {
            int n = n0 + r;
            if (n < Nn) {
                if (isbf) {
                    uint4 q = *reinterpret_cast<const uint4*>(xb + (size_t)n * 128 + ko * 8);
                    xv[r][0] = bf2f(q.x & 0xffffu); xv[r][1] = bf2f(q.x >> 16);
                    xv[r][2] = bf2f(q.y & 0xffffu); xv[r][3] = bf2f(q.y >> 16);
                    xv[r][4] = bf2f(q.z & 0xffffu); xv[r][5] = bf2f(q.z >> 16);
                    xv[r][6] = bf2f(q.w & 0xffffu); xv[r][7] = bf2f(q.w >> 16);
                } else {
                    const float4* p = reinterpret_cast<const float4*>(xf + (size_t)n * 128 + ko * 8);
                    float4 a = p[0], b = p[1];
                    xv[r][0] = a.x; xv[r][1] = a.y; xv[r][2] = a.z; xv[r][3] = a.w;
                    xv[r][4] = b.x; xv[r][5] = b.y; xv[r][6] = b.z; xv[r][7] = b.w;
                }
            } else {
                #pragma unroll
                for (int u = 0; u < 8; ++u) xv[r][u] = 0.f;
            }
        }
        #pragma unroll
        for (int c = 0; c < 4; ++c) {
            const float* wr = &sWt[(hq * 4 + c) * 132 + ko * 8];
            float4 w0 = *reinterpret_cast<const float4*>(wr);
            float4 w1v = *reinterpret_cast<const float4*>(wr + 4);
            #pragma unroll
            for (int r = 0; r < 4; ++r) {
                acc[r][c] += xv[r][0] * w0.x + xv[r][1] * w0.y + xv[r][2] * w0.z + xv[r][3] * w0.w
                           + xv[r][4] * w1v.x + xv[r][5] * w1v.y + xv[r][6] * w1v.z + xv[r][7] * w1v.w;
            }
        }
    }
    #pragma unroll
    for (int r = 0; r < 4; ++r) {
        int n = n0 + r;
        if (n < Nn) {
            float dv = rsqrtf((float)(deg[n] + 1));  // +1 self loop
            if (hq == 0) dinv[n] = dv;
            float4 o = make_float4(acc[r][0] * dv, acc[r][1] * dv, acc[r][2] * dv, acc[r][3] * dv);
            *reinterpret_cast<float4*>(hs + (size_t)n * 16 + hq * 4) = o;
            float4 a0 = make_float4(o.x * dv, o.y * dv, o.z * dv, o.w * dv);
            *reinterpret_cast<float4*>(agg + (size_t)n * 16 + hq * 4) = a0;
        }
    }
}

// ---------------- kernel 3: edge scatter-add (HW fp32 atomics) ----------------
// 16 consecutive lanes share an edge -> the 16 atomics hit one 64B line of agg
__global__ __launch_bounds__(256) void k_edge(const int* __restrict__ ei,
                                              const int* __restrict__ flags,
                                              const float* __restrict__ dinv,
                                              const float* __restrict__ hs,
                                              float* __restrict__ agg, int E, int Nn) {
    int t = blockIdx.x * 256 + threadIdx.x;
    int e = t >> 4, j = t & 15;
    if (e >= E) return;
    int is64 = flags[1];
    int s, d;
    if (is64) { s = ei[2 * e]; d = ei[2 * (E + e)]; }
    else      { s = ei[e];     d = ei[E + e]; }
    if ((unsigned)s >= (unsigned)Nn || (unsigned)d >= (unsigned)Nn) return;  // defensive
    float w = dinv[d];
    atomAddF(&agg[(size_t)d * 16 + j], hs[(size_t)s * 16 + j] * w);
}

// ---------------- kernel 4: bias+relu -> @Wp+bp -> softmax -> out ----------------
__global__ __launch_bounds__(256) void k_final(const float* __restrict__ agg,
                                               const void* __restrict__ b1raw,
                                               const void* __restrict__ wpraw,
                                               const void* __restrict__ bpraw,
                                               const int* __restrict__ flags,
                                               void* __restrict__ outraw, int Nn) {
    __shared__ float sWp[256];
    __shared__ float sA[256];
    const int isbf = flags[0];
    int tid = threadIdx.x;
    sWp[tid] = isbf ? bf2f(((const ushort*)wpraw)[tid]) : ((const float*)wpraw)[tid];
    int n0 = blockIdx.x * 16;
    int nl = tid >> 4, c = tid & 15;
    int n = n0 + nl;
    float b1v = isbf ? bf2f(((const ushort*)b1raw)[c]) : ((const float*)b1raw)[c];
    float bpv = isbf ? bf2f(((const ushort*)bpraw)[c]) : ((const float*)bpraw)[c];
    float av = (n < Nn) ? agg[(size_t)n * 16 + c] : 0.f;
    sA[tid] = fmaxf(av + b1v, 0.f);
    __syncthreads();
    float acc = bpv;
    #pragma unroll
    for (int j = 0; j < 16; ++j) acc += sA[nl * 16 + j] * sWp[j * 16 + c];
    float m = acc;
    #pragma unroll
    for (int off = 1; off < 16; off <<= 1) m = fmaxf(m, __shfl_xor(m, off, 16));
    float ev = __expf(acc - m);
    float s = ev;
    #pragma unroll
    for (int off = 1; off < 16; off <<= 1) s += __shfl_xor(s, off, 16);
    if (n < Nn) {
        float v = ev / s;
        if (isbf) ((ushort*)outraw)[(size_t)n * 16 + c] = f2bf(v);
        else      ((float*)outraw)[(size_t)n * 16 + c] = v;
    }
}

extern "C" void kernel_launch(void* const* d_in, const int* in_sizes, int n_in,
                              void* d_out, int out_size, void* d_ws, size_t ws_size,
                              hipStream_t stream) {
    const void* x  = d_in[0];             // [N,128]
    const void* W1 = d_in[1];             // [128,16]
    const void* b1 = d_in[2];             // [16]
    const void* Wp = d_in[3];             // [16,16]
    const void* bp = d_in[4];             // [16]
    const int*  ei = (const int*)d_in[5]; // [2,E] int32 or int64

    int Nn = in_sizes[0] / 128;
    int E  = in_sizes[5] / 2;

    size_t Ns = (size_t)Nn;
    char* ws = (char*)d_ws;
    size_t off = 0;
    auto alloc = [&](size_t bytes) { void* p = ws + off; off += (bytes + 63) & ~(size_t)63; return p; };
    int*   flags = (int*)alloc(64);
    float* hs    = (float*)alloc(Ns * 16 * 4);
    float* agg   = (float*)alloc(Ns * 16 * 4);
    float* dinv  = (float*)alloc(Ns * 4);
    int*   deg   = (int*)alloc(Ns * 4);

    int G  = (Nn + 255) / 256;
    int EB = (E + 255) / 256;

    hipMemsetAsync(deg, 0, Ns * 4, stream);
    k_detect<<<1, 256, 0, stream>>>((const unsigned int*)x, (const unsigned int*)ei, flags);
    k_deg<<<EB, 256, 0, stream>>>(ei, flags, deg, E, Nn);
    k_gemm1<<<G, 256, 0, stream>>>(x, W1, flags, deg, hs, agg, dinv, Nn);
    int edge_blocks = (int)(((size_t)E * 16 + 255) / 256);
    k_edge<<<edge_blocks, 256, 0, stream>>>(ei, flags, dinv, hs, agg, E, Nn);
    k_final<<<(Nn + 15) / 16, 256, 0, stream>>>(agg, b1, Wp, bp, flags, d_out, Nn);
}